// Round 3
// baseline (635.054 us; speedup 1.0000x reference)
//
#include <hip/hip_runtime.h>
#include <hip/hip_cooperative_groups.h>
#include <math.h>

namespace cg = cooperative_groups;

#define NPTS   32768
#define NK     4
#define GRIDN  16
#define CIN    64
#define COUT   64
#define NCELLS (NK*GRIDN*GRIDN*GRIDN)   /* 16384 */
#define CAP    128                      /* bucket capacity; mean fill = 16 */

typedef __attribute__((ext_vector_type(8))) short  short8;
typedef __attribute__((ext_vector_type(4))) float  f32x4;

static __device__ inline unsigned short f2bf(float f) {
    unsigned int u = __builtin_bit_cast(unsigned int, f);
    unsigned int r = u + 0x7fff + ((u >> 16) & 1);   // RNE truncate to bf16
    return (unsigned short)(r >> 16);
}

// ---------------------------------------------------------------------------
// Fused cooperative kernel: one dispatch, three phases, two grid syncs.
//   A: zero cnt + out          (replaces memset + scatter-side zeroing)
//   B: scatter (point,corner) entries into fixed-capacity buckets
//   C: one WAVE per cell: B-frags direct from global (round-1 body, verified),
//      entries in 16-row batches, 8x mfma_16x16x32_bf16, fp32 atomic epilogue
// Grid is sized for exact co-residency (cooperative requirement); all phases
// are grid-stride so any grid size is correct.
//
// Fragment layouts (gfx950, verified by the passing predecessor kernels):
//   A[m][k]: m = lane&15, k = (lane>>4)*8 + j
//   B[k][n]: n = lane&15, k = (lane>>4)*8 + j
//   D[m][n]: n = lane&15, m = (lane>>4)*4 + reg
// ---------------------------------------------------------------------------
__global__ __launch_bounds__(256, 4)
void k_fused(const int* __restrict__ pidx, const float* __restrict__ pos,
             const float* __restrict__ xs, const float* __restrict__ kernels,
             const float* __restrict__ biases, int* __restrict__ cnt,
             int2* __restrict__ ent, float* __restrict__ out,
             int out_elems, int n, int cap) {
    cg::grid_group grid = cg::this_grid();
    int T  = gridDim.x * blockDim.x;
    int t0 = blockIdx.x * blockDim.x + threadIdx.x;

    // ---- Phase A: zero cnt and out ----
    for (int i = t0; i < NCELLS; i += T) cnt[i] = 0;
    {
        float4 z = {0.f, 0.f, 0.f, 0.f};
        int nv = out_elems >> 2;
        for (int i = t0; i < nv; i += T) *(float4*)&out[i << 2] = z;
    }
    __threadfence();
    grid.sync();

    // ---- Phase B: scatter entries ----
    int items = n * 8;
    for (int it = t0; it < items; it += T) {
        int p  = it >> 3;
        int c  = it & 7;
        int pk = pidx[p];
        float lx = pos[3*p+0]*16.f - 0.5f;
        float ly = pos[3*p+1]*16.f - 0.5f;
        float lz = pos[3*p+2]*16.f - 0.5f;
        float flx = floorf(lx), fly = floorf(ly), flz = floorf(lz);
        float tx = lx - flx, ty = ly - fly, tz = lz - flz;
        int fx = (int)flx, fy = (int)fly, fz = (int)flz;
        int c0 = c & 1, c1 = (c >> 1) & 1, c2 = (c >> 2) & 1;
        int ix = min(max(fx + c0, 0), GRIDN-1);
        int iy = min(max(fy + c1, 0), GRIDN-1);
        int iz = min(max(fz + c2, 0), GRIDN-1);
        float w = (c0 ? tx : 1.f - tx) * (c1 ? ty : 1.f - ty) * (c2 ? tz : 1.f - tz);
        int cell = ((pk*GRIDN + iz)*GRIDN + iy)*GRIDN + ix;
        int e = atomicAdd(&cnt[cell], 1);
        if (e < cap) ent[(size_t)cell * cap + e] = make_int2(p, __float_as_int(w));
    }
    __threadfence();
    grid.sync();

    // ---- Phase C: one wave per cell, grid-stride over cells ----
    int l  = t0 & 63;
    int gw = t0 >> 6;         // global wave id
    int nw = T >> 6;          // total waves
    int q  = l >> 4;          // k-chunk / D row-quad
    int m  = l & 15;          // A-row / B-col / D-col

    for (int cell = gw; cell < NCELLS; cell += nw) {
        int count = min(cnt[cell], cap);
        if (count == 0) continue;

        // B fragments for all 4 cout-chunks, direct from global
        const float* Kg = kernels + (size_t)cell * (CIN * COUT);
        short8 Bf[4][2];
#pragma unroll
        for (int c = 0; c < 4; ++c)
#pragma unroll
            for (int s = 0; s < 2; ++s)
#pragma unroll
                for (int j = 0; j < 8; ++j)
                    Bf[c][s][j] = (short)f2bf(Kg[(s*32 + q*8 + j)*COUT + c*16 + m]);

        float bias_c[4];
#pragma unroll
        for (int c = 0; c < 4; ++c)
            bias_c[c] = biases[(size_t)cell * COUT + c*16 + m];

        const int2* eb = ent + (size_t)cell * cap;
        int nb = (count + 15) >> 4;
        for (int b = 0; b < nb; ++b) {
            int r0 = b << 4;
            int2 em = (r0 + m < count) ? eb[r0 + m] : make_int2(0, 0);
            int apid = em.x;   // pad rows read row 0 (finite), w=0 skips epilogue

            short8 af[2];
#pragma unroll
            for (int s = 0; s < 2; ++s) {
                const float4 x0 = *(const float4*)&xs[(size_t)apid*CIN + s*32 + q*8 + 0];
                const float4 x1 = *(const float4*)&xs[(size_t)apid*CIN + s*32 + q*8 + 4];
                af[s][0] = (short)f2bf(x0.x); af[s][1] = (short)f2bf(x0.y);
                af[s][2] = (short)f2bf(x0.z); af[s][3] = (short)f2bf(x0.w);
                af[s][4] = (short)f2bf(x1.x); af[s][5] = (short)f2bf(x1.y);
                af[s][6] = (short)f2bf(x1.z); af[s][7] = (short)f2bf(x1.w);
            }

            f32x4 acc[4];
#pragma unroll
            for (int c = 0; c < 4; ++c) acc[c] = (f32x4){0.f, 0.f, 0.f, 0.f};
#pragma unroll
            for (int s = 0; s < 2; ++s)
#pragma unroll
                for (int c = 0; c < 4; ++c)
                    acc[c] = __builtin_amdgcn_mfma_f32_16x16x32_bf16(af[s], Bf[c][s], acc[c], 0, 0, 0);

#pragma unroll
            for (int reg = 0; reg < 4; ++reg) {
                int   r     = q*4 + reg;
                int   pid_r = __shfl(em.x, r);
                float w_r   = __shfl(__int_as_float(em.y), r);
                if (w_r != 0.f) {
                    float* orow = out + (size_t)pid_r * COUT + m;
#pragma unroll
                    for (int c = 0; c < 4; ++c)
                        unsafeAtomicAdd(&orow[c*16], w_r * (acc[c][reg] + bias_c[c]));
                }
            }
        }
    }
}

// ---------------------------------------------------------------------------
// Fallback pipeline (verified round-2 kernels), used only if cooperative
// launch is unavailable.
// ---------------------------------------------------------------------------
__global__ void k_scatter(const int* __restrict__ pidx, const float* __restrict__ pos,
                          int* __restrict__ cnt, int2* __restrict__ ent,
                          float* __restrict__ out, int out_elems,
                          int n, int cap) {
    int t = blockIdx.x * blockDim.x + threadIdx.x;
    {
        int o = t * 8;
        if (o + 8 <= out_elems) {
            float4 z = {0.f, 0.f, 0.f, 0.f};
            *(float4*)&out[o + 0] = z;
            *(float4*)&out[o + 4] = z;
        }
    }
    int p = t >> 3;
    if (p >= n) return;
    int c  = t & 7;
    int pk = pidx[p];
    float lx = pos[3*p+0]*16.f - 0.5f;
    float ly = pos[3*p+1]*16.f - 0.5f;
    float lz = pos[3*p+2]*16.f - 0.5f;
    float flx = floorf(lx), fly = floorf(ly), flz = floorf(lz);
    float tx = lx - flx, ty = ly - fly, tz = lz - flz;
    int fx = (int)flx, fy = (int)fly, fz = (int)flz;
    int c0 = c & 1, c1 = (c >> 1) & 1, c2 = (c >> 2) & 1;
    int ix = min(max(fx + c0, 0), GRIDN-1);
    int iy = min(max(fy + c1, 0), GRIDN-1);
    int iz = min(max(fz + c2, 0), GRIDN-1);
    float w = (c0 ? tx : 1.f - tx) * (c1 ? ty : 1.f - ty) * (c2 ? tz : 1.f - tz);
    int cell = ((pk*GRIDN + iz)*GRIDN + iy)*GRIDN + ix;
    int e = atomicAdd(&cnt[cell], 1);
    if (e < cap) ent[(size_t)cell * cap + e] = make_int2(p, __float_as_int(w));
}

__global__ __launch_bounds__(256)
void k_main(const float* __restrict__ xs, const float* __restrict__ kernels,
            const float* __restrict__ biases, const int* __restrict__ cnt,
            const int2* __restrict__ ent, float* __restrict__ out, int cap) {
    int tid  = threadIdx.x;
    int wv   = tid >> 6;
    int l    = tid & 63;
    int q    = l >> 4;
    int m    = l & 15;
    int cell = blockIdx.x * 4 + wv;

    int count = min(cnt[cell], cap);
    if (count == 0) return;

    const float* Kg = kernels + (size_t)cell * (CIN * COUT);
    short8 Bf[4][2];
#pragma unroll
    for (int c = 0; c < 4; ++c)
#pragma unroll
        for (int s = 0; s < 2; ++s)
#pragma unroll
            for (int j = 0; j < 8; ++j)
                Bf[c][s][j] = (short)f2bf(Kg[(s*32 + q*8 + j)*COUT + c*16 + m]);

    float bias_c[4];
#pragma unroll
    for (int c = 0; c < 4; ++c)
        bias_c[c] = biases[(size_t)cell * COUT + c*16 + m];

    const int2* eb = ent + (size_t)cell * cap;
    int nb = (count + 15) >> 4;
    for (int b = 0; b < nb; ++b) {
        int r0 = b << 4;
        int2 em = (r0 + m < count) ? eb[r0 + m] : make_int2(0, 0);
        int apid = em.x;

        short8 af[2];
#pragma unroll
        for (int s = 0; s < 2; ++s) {
            const float4 x0 = *(const float4*)&xs[(size_t)apid*CIN + s*32 + q*8 + 0];
            const float4 x1 = *(const float4*)&xs[(size_t)apid*CIN + s*32 + q*8 + 4];
            af[s][0] = (short)f2bf(x0.x); af[s][1] = (short)f2bf(x0.y);
            af[s][2] = (short)f2bf(x0.z); af[s][3] = (short)f2bf(x0.w);
            af[s][4] = (short)f2bf(x1.x); af[s][5] = (short)f2bf(x1.y);
            af[s][6] = (short)f2bf(x1.z); af[s][7] = (short)f2bf(x1.w);
        }

        f32x4 acc[4];
#pragma unroll
        for (int c = 0; c < 4; ++c) acc[c] = (f32x4){0.f, 0.f, 0.f, 0.f};
#pragma unroll
        for (int s = 0; s < 2; ++s)
#pragma unroll
            for (int c = 0; c < 4; ++c)
                acc[c] = __builtin_amdgcn_mfma_f32_16x16x32_bf16(af[s], Bf[c][s], acc[c], 0, 0, 0);

#pragma unroll
        for (int reg = 0; reg < 4; ++reg) {
            int   r     = q*4 + reg;
            int   pid_r = __shfl(em.x, r);
            float w_r   = __shfl(__int_as_float(em.y), r);
            if (w_r != 0.f) {
                float* orow = out + (size_t)pid_r * COUT + m;
#pragma unroll
                for (int c = 0; c < 4; ++c)
                    unsafeAtomicAdd(&orow[c*16], w_r * (acc[c][reg] + bias_c[c]));
            }
        }
    }
}

// ---------------------------------------------------------------------------
extern "C" void kernel_launch(void* const* d_in, const int* in_sizes, int n_in,
                              void* d_out, int out_size, void* d_ws, size_t ws_size,
                              hipStream_t stream) {
    const int*   pidx    = (const int*)  d_in[0];
    const float* pos     = (const float*)d_in[1];
    const float* xs      = (const float*)d_in[2];
    const float* kernels = (const float*)d_in[3];
    const float* biases  = (const float*)d_in[4];
    float*       out     = (float*)d_out;
    int n = in_sizes[0];   // 32768
    int out_elems = out_size;

    // ws layout: cnt[NCELLS] ints | ent[NCELLS*CAP] int2
    int*  cnt = (int*)d_ws;
    int2* ent = (int2*)((char*)d_ws + (size_t)NCELLS * sizeof(int));

    int cap = CAP;
    size_t avail = (ws_size > (size_t)NCELLS * sizeof(int))
                 ? (ws_size - (size_t)NCELLS * sizeof(int)) / (sizeof(int2) * NCELLS)
                 : 0;
    if ((size_t)cap > avail) cap = (int)avail;

    // grid size for exact co-residency (computed once, cached)
    static int s_blocks = 0;
    static int s_coop_ok = -1;
    if (s_blocks == 0) {
        int occ = 0;
        hipError_t e = hipOccupancyMaxActiveBlocksPerMultiprocessor(
            &occ, (const void*)k_fused, 256, 0);
        if (e != hipSuccess || occ < 1) occ = 4;
        long b = (long)occ * 256;            // 256 CUs on MI355X
        if (b > 4096) b = 4096;
        if (b < 256)  b = 256;
        s_blocks = (int)b;
    }

    if (s_coop_ok != 0) {
        void* args[] = { (void*)&pidx, (void*)&pos, (void*)&xs, (void*)&kernels,
                         (void*)&biases, (void*)&cnt, (void*)&ent, (void*)&out,
                         (void*)&out_elems, (void*)&n, (void*)&cap };
        hipError_t e = hipLaunchCooperativeKernel((const void*)k_fused,
                                                  dim3(s_blocks), dim3(256),
                                                  args, 0, stream);
        if (e == hipSuccess) { s_coop_ok = 1; return; }
        s_coop_ok = 0;   // fall through to 3-dispatch pipeline
    }

    hipMemsetAsync(cnt, 0, NCELLS * sizeof(int), stream);
    int eblocks = (n * 8 + 255) / 256;
    k_scatter<<<eblocks, 256, 0, stream>>>(pidx, pos, cnt, ent, out, out_elems, n, cap);
    k_main  <<<NCELLS/4, 256, 0, stream>>>(xs, kernels, biases, cnt, ent, out, cap);
}

// Round 4
// 410.614 us; speedup vs baseline: 1.5466x; 1.5466x over previous
//
#include <hip/hip_runtime.h>
#include <math.h>

#define NPTS   32768
#define NK     4
#define GRIDN  16
#define CIN    64
#define COUT   64
#define NCELLS (NK*GRIDN*GRIDN*GRIDN)   /* 16384 */
#define CAP    128                      /* bucket capacity; mean fill = 16, max corner-cell ~54 */

typedef __attribute__((ext_vector_type(8))) short  short8;
typedef __attribute__((ext_vector_type(4))) float  f32x4;

static __device__ inline unsigned short f2bf(float f) {
    unsigned int u = __builtin_bit_cast(unsigned int, f);
    unsigned int r = u + 0x7fff + ((u >> 16) & 1);   // RNE truncate to bf16
    return (unsigned short)(r >> 16);
}

// ---------------------------------------------------------------------------
// Pass 1: scatter (point,corner) entries into fixed-capacity buckets, with
// the corner id packed into ent.x (bits 20..22). (corner,point) is globally
// unique -> enables atomic-free deterministic stores in k_main.
// Also converts xs fp32 -> bf16 into xb (one coalesced pass; halves the
// gathered A-payload in k_main and removes per-batch cvt chains).
// ---------------------------------------------------------------------------
__global__ void k_scatter(const int* __restrict__ pidx, const float* __restrict__ pos,
                          const float* __restrict__ xs, unsigned short* __restrict__ xb,
                          int* __restrict__ cnt, int2* __restrict__ ent,
                          int n, int cap) {
    int t = blockIdx.x * blockDim.x + threadIdx.x;

    {   // xs -> bf16: thread t converts 8 floats; 262144 threads x 8 = 2M exact
        int o = t * 8;
        if (o + 8 <= n * CIN) {
            float4 a = *(const float4*)&xs[o + 0];
            float4 b = *(const float4*)&xs[o + 4];
            ushort4 lo = { f2bf(a.x), f2bf(a.y), f2bf(a.z), f2bf(a.w) };
            ushort4 hi = { f2bf(b.x), f2bf(b.y), f2bf(b.z), f2bf(b.w) };
            *(ushort4*)&xb[o + 0] = lo;
            *(ushort4*)&xb[o + 4] = hi;
        }
    }

    int p = t >> 3;
    if (p >= n) return;
    int c  = t & 7;
    int pk = pidx[p];
    float lx = pos[3*p+0]*16.f - 0.5f;
    float ly = pos[3*p+1]*16.f - 0.5f;
    float lz = pos[3*p+2]*16.f - 0.5f;
    float flx = floorf(lx), fly = floorf(ly), flz = floorf(lz);
    float tx = lx - flx, ty = ly - fly, tz = lz - flz;
    int fx = (int)flx, fy = (int)fly, fz = (int)flz;
    int c0 = c & 1, c1 = (c >> 1) & 1, c2 = (c >> 2) & 1;
    int ix = min(max(fx + c0, 0), GRIDN-1);
    int iy = min(max(fy + c1, 0), GRIDN-1);
    int iz = min(max(fz + c2, 0), GRIDN-1);
    float w = (c0 ? tx : 1.f - tx) * (c1 ? ty : 1.f - ty) * (c2 ? tz : 1.f - tz);
    int cell = ((pk*GRIDN + iz)*GRIDN + iy)*GRIDN + ix;
    int e = atomicAdd(&cnt[cell], 1);
    if (e < cap) ent[(size_t)cell * cap + e] = make_int2(p | (c << 20), __float_as_int(w));
}

// ---------------------------------------------------------------------------
// Pass 2: one wave per cell (16384 waves). B-frags direct from global
// (verified equal to LDS staging). Entries in 16-row batches, 8x
// mfma_16x16x32_bf16. Epilogue: PLAIN STORES to stage[c][p][col] — the
// (c,p,col) key is unique, so no atomics and no zero-init needed (every
// (c,p) row is written exactly once across the dispatch).
//
// Fragment layouts (gfx950, verified by all passing predecessors):
//   A[m][k]: m = lane&15, k = (lane>>4)*8 + j
//   B[k][n]: n = lane&15, k = (lane>>4)*8 + j
//   D[m][n]: n = lane&15, m = (lane>>4)*4 + reg
// ---------------------------------------------------------------------------
__global__ __launch_bounds__(256)
void k_main(const unsigned short* __restrict__ xb, const float* __restrict__ kernels,
            const float* __restrict__ biases, const int* __restrict__ cnt,
            const int2* __restrict__ ent, float* __restrict__ stage, int cap) {
    int tid  = threadIdx.x;
    int wv   = tid >> 6;
    int l    = tid & 63;
    int q    = l >> 4;        // k-chunk / D row-quad
    int m    = l & 15;        // A-row / B-col / D-col
    int cell = blockIdx.x * 4 + wv;

    int count = min(cnt[cell], cap);
    const int2* eb = ent + (size_t)cell * cap;

    // issue batch-0 entry load before the 64 K-loads (independent; hides)
    int2 em = (m < count) ? eb[m] : make_int2(0, 0);

    // ---- B fragments for all 4 cout-chunks, direct from global ----
    const float* Kg = kernels + (size_t)cell * (CIN * COUT);
    short8 Bf[4][2];
#pragma unroll
    for (int c = 0; c < 4; ++c)
#pragma unroll
        for (int s = 0; s < 2; ++s)
#pragma unroll
            for (int j = 0; j < 8; ++j)
                Bf[c][s][j] = (short)f2bf(Kg[(s*32 + q*8 + j)*COUT + c*16 + m]);

    float bias_c[4];
#pragma unroll
    for (int c = 0; c < 4; ++c)
        bias_c[c] = biases[(size_t)cell * COUT + c*16 + m];

    int nb = (count + 15) >> 4;
    for (int b = 0; b < nb; ++b) {
        int r0 = b << 4;
        // prefetch next batch's entry record
        int2 em_n = make_int2(0, 0);
        if (b + 1 < nb && r0 + 16 + m < count) em_n = eb[r0 + 16 + m];

        int apid = em.x & 0xFFFFF;   // pad rows read row 0 (finite); guarded below

        // ---- A fragments: bf16, one 16B load per k-half ----
        short8 af[2];
#pragma unroll
        for (int s = 0; s < 2; ++s)
            af[s] = *(const short8*)&xb[(size_t)apid*CIN + s*32 + q*8];

        f32x4 acc[4];
#pragma unroll
        for (int c = 0; c < 4; ++c) acc[c] = (f32x4){0.f, 0.f, 0.f, 0.f};
#pragma unroll
        for (int s = 0; s < 2; ++s)
#pragma unroll
            for (int c = 0; c < 4; ++c)
                acc[c] = __builtin_amdgcn_mfma_f32_16x16x32_bf16(af[s], Bf[c][s], acc[c], 0, 0, 0);

        // ---- epilogue: deterministic stores; D row r lives on lane r ----
#pragma unroll
        for (int reg = 0; reg < 4; ++reg) {
            int   r     = q*4 + reg;
            int   key_r = __shfl(em.x, r);
            float w_r   = __shfl(__int_as_float(em.y), r);
            if (r0 + r < count) {
                int pid_r = key_r & 0xFFFFF;
                int c_r   = key_r >> 20;
                float* srow = stage + ((size_t)c_r * NPTS + pid_r) * COUT + m;
#pragma unroll
                for (int c = 0; c < 4; ++c)
                    srow[c*16] = w_r * (acc[c][reg] + bias_c[c]);
            }
        }
        em = em_n;
    }
}

// ---------------------------------------------------------------------------
// Pass 3: streaming reduce of the 8 corner slabs. Thread t handles 4 cols of
// one point: fully coalesced reads (each slab is [p][col] row-major) and
// writes. out needs no pre-zeroing.
// ---------------------------------------------------------------------------
__global__ __launch_bounds__(256)
void k_reduce(const float* __restrict__ stage, float* __restrict__ out) {
    int t  = blockIdx.x * blockDim.x + threadIdx.x;   // 524288 = 32768*16
    int p  = t >> 4;
    int c4 = (t & 15) << 2;
    size_t off = (size_t)p * COUT + c4;
    float4 s = *(const float4*)&stage[off];
#pragma unroll
    for (int c = 1; c < 8; ++c) {
        float4 v = *(const float4*)&stage[(size_t)c * NPTS * COUT + off];
        s.x += v.x; s.y += v.y; s.z += v.z; s.w += v.w;
    }
    *(float4*)&out[off] = s;
}

// ---------------------------------------------------------------------------
extern "C" void kernel_launch(void* const* d_in, const int* in_sizes, int n_in,
                              void* d_out, int out_size, void* d_ws, size_t ws_size,
                              hipStream_t stream) {
    const int*   pidx    = (const int*)  d_in[0];
    const float* pos     = (const float*)d_in[1];
    const float* xs      = (const float*)d_in[2];
    const float* kernels = (const float*)d_in[3];
    const float* biases  = (const float*)d_in[4];
    float*       out     = (float*)d_out;
    int n = in_sizes[0];   // 32768

    // ws layout: cnt[NCELLS] int | ent[NCELLS*CAP] int2 | xb[N*CIN] bf16
    //            | stage[8*NPTS*COUT] float   (~84 MB total)
    char* w = (char*)d_ws;
    int*            cnt   = (int*)w;                 w += (size_t)NCELLS * sizeof(int);
    int2*           ent   = (int2*)w;                w += (size_t)NCELLS * CAP * sizeof(int2);
    unsigned short* xb    = (unsigned short*)w;      w += (size_t)NPTS * CIN * sizeof(unsigned short);
    float*          stage = (float*)w;

    int cap = CAP;   // ws is >= 1 GiB in this harness; layout uses ~84 MB

    hipMemsetAsync(cnt, 0, NCELLS * sizeof(int), stream);

    int eblocks = (n * 8 + 255) / 256;
    k_scatter<<<eblocks, 256, 0, stream>>>(pidx, pos, xs, xb, cnt, ent, n, cap);
    k_main  <<<NCELLS/4, 256, 0, stream>>>(xb, kernels, biases, cnt, ent, stage, cap);
    k_reduce<<<(NPTS*16)/256, 256, 0, stream>>>(stage, out);
}

// Round 5
// 389.954 us; speedup vs baseline: 1.6285x; 1.0530x over previous
//
#include <hip/hip_runtime.h>
#include <math.h>

#define NPTS   32768
#define NK     4
#define GRIDN  16
#define CIN    64
#define COUT   64
#define NCELLS (NK*GRIDN*GRIDN*GRIDN)   /* 16384 */
#define CAP    128                      /* bucket capacity; mean fill = 16 */

typedef __attribute__((ext_vector_type(8))) short  short8;
typedef __attribute__((ext_vector_type(4))) float  f32x4;

static __device__ inline unsigned short f2bf(float f) {
    unsigned int u = __builtin_bit_cast(unsigned int, f);
    unsigned int r = u + 0x7fff + ((u >> 16) & 1);   // RNE truncate to bf16
    return (unsigned short)(r >> 16);
}

// ---------------------------------------------------------------------------
// Pass 1: scatter (point,corner) entries into fixed-capacity buckets.
// One thread per (point,corner). Also zeroes the output buffer (replaces a
// separate memset dispatch): thread t zeroes out[8t..8t+8).
// ---------------------------------------------------------------------------
__global__ void k_scatter(const int* __restrict__ pidx, const float* __restrict__ pos,
                          int* __restrict__ cnt, int2* __restrict__ ent,
                          float* __restrict__ out, int out_elems,
                          int n, int cap) {
    int t = blockIdx.x * blockDim.x + threadIdx.x;
    {
        int o = t * 8;
        if (o + 8 <= out_elems) {
            float4 z = {0.f, 0.f, 0.f, 0.f};
            *(float4*)&out[o + 0] = z;
            *(float4*)&out[o + 4] = z;
        }
    }
    int p = t >> 3;
    if (p >= n) return;
    int c  = t & 7;
    int pk = pidx[p];
    float lx = pos[3*p+0]*16.f - 0.5f;
    float ly = pos[3*p+1]*16.f - 0.5f;
    float lz = pos[3*p+2]*16.f - 0.5f;
    float flx = floorf(lx), fly = floorf(ly), flz = floorf(lz);
    float tx = lx - flx, ty = ly - fly, tz = lz - flz;
    int fx = (int)flx, fy = (int)fly, fz = (int)flz;
    int c0 = c & 1, c1 = (c >> 1) & 1, c2 = (c >> 2) & 1;
    int ix = min(max(fx + c0, 0), GRIDN-1);
    int iy = min(max(fy + c1, 0), GRIDN-1);
    int iz = min(max(fz + c2, 0), GRIDN-1);
    float w = (c0 ? tx : 1.f - tx) * (c1 ? ty : 1.f - ty) * (c2 ? tz : 1.f - tz);
    int cell = ((pk*GRIDN + iz)*GRIDN + iy)*GRIDN + ix;
    int e = atomicAdd(&cnt[cell], 1);
    if (e < cap) ent[(size_t)cell * cap + e] = make_int2(p, __float_as_int(w));
}

// ---------------------------------------------------------------------------
// Pass 2: FOUR WAVES PER CELL — wave wv owns cout-chunk [wv*16, wv*16+16).
// Each wave loads only its 4 KB K-slice (16 dword loads; lanes m=0..15 give
// 64B segments, 4 rows per instr). Same aggregate K traffic as before, but
// 4x the wave-level miss concurrency on the K stream. No LDS, no barriers.
// Entries stream in 16-row batches; 2x mfma_16x16x32_bf16 per batch;
// epilogue: 4 fp32 HW atomics per lane per batch (proven not a bottleneck
// by the round-4 A/B).
//
// Fragment layouts (gfx950, verified by all passing predecessors):
//   A[m][k]: m = lane&15, k = (lane>>4)*8 + j
//   B[k][n]: n = lane&15, k = (lane>>4)*8 + j
//   D[m][n]: n = lane&15, m = (lane>>4)*4 + reg
// ---------------------------------------------------------------------------
__global__ __launch_bounds__(256)
void k_main(const float* __restrict__ xs, const float* __restrict__ kernels,
            const float* __restrict__ biases, const int* __restrict__ cnt,
            const int2* __restrict__ ent, float* __restrict__ out, int cap) {
    int tid  = threadIdx.x;
    int wv   = tid >> 6;      // cout chunk 0..3
    int l    = tid & 63;
    int q    = l >> 4;        // k-chunk / D row-quad
    int m    = l & 15;        // A-row / B-col / D-col
    int cell = blockIdx.x;

    int count = min(cnt[cell], cap);
    if (count == 0) return;
    const int2* eb = ent + (size_t)cell * cap;

    // issue batch-0 entry load early (independent of K loads)
    int2 em = (m < count) ? eb[m] : make_int2(0, 0);

    // ---- B fragments for THIS wave's cout-chunk, direct from global ----
    const float* Kg = kernels + (size_t)cell * (CIN * COUT);
    short8 Bf[2];
#pragma unroll
    for (int s = 0; s < 2; ++s)
#pragma unroll
        for (int j = 0; j < 8; ++j)
            Bf[s][j] = (short)f2bf(Kg[(s*32 + q*8 + j)*COUT + wv*16 + m]);

    float bias_c = biases[(size_t)cell * COUT + wv*16 + m];

    int nb = (count + 15) >> 4;
    for (int b = 0; b < nb; ++b) {
        int r0 = b << 4;
        // prefetch next batch's entry record
        int2 em_n = make_int2(0, 0);
        if (b + 1 < nb && r0 + 16 + m < count) em_n = eb[r0 + 16 + m];

        int apid = em.x;   // pad rows read row 0 (finite), w=0 skips epilogue

        // ---- A fragments: 8 consecutive floats per lane per k-half ----
        short8 af[2];
#pragma unroll
        for (int s = 0; s < 2; ++s) {
            const float4 x0 = *(const float4*)&xs[(size_t)apid*CIN + s*32 + q*8 + 0];
            const float4 x1 = *(const float4*)&xs[(size_t)apid*CIN + s*32 + q*8 + 4];
            af[s][0] = (short)f2bf(x0.x); af[s][1] = (short)f2bf(x0.y);
            af[s][2] = (short)f2bf(x0.z); af[s][3] = (short)f2bf(x0.w);
            af[s][4] = (short)f2bf(x1.x); af[s][5] = (short)f2bf(x1.y);
            af[s][6] = (short)f2bf(x1.z); af[s][7] = (short)f2bf(x1.w);
        }

        f32x4 acc = {0.f, 0.f, 0.f, 0.f};
#pragma unroll
        for (int s = 0; s < 2; ++s)
            acc = __builtin_amdgcn_mfma_f32_16x16x32_bf16(af[s], Bf[s], acc, 0, 0, 0);

        // ---- epilogue: D row r = q*4+reg lives on lane r (r<16) -> shfl ----
#pragma unroll
        for (int reg = 0; reg < 4; ++reg) {
            int   r     = q*4 + reg;
            int   pid_r = __shfl(em.x, r);
            float w_r   = __shfl(__int_as_float(em.y), r);
            if (w_r != 0.f) {
                unsafeAtomicAdd(&out[(size_t)pid_r * COUT + wv*16 + m],
                                w_r * (acc[reg] + bias_c));
            }
        }
        em = em_n;
    }
}

// ---------------------------------------------------------------------------
extern "C" void kernel_launch(void* const* d_in, const int* in_sizes, int n_in,
                              void* d_out, int out_size, void* d_ws, size_t ws_size,
                              hipStream_t stream) {
    const int*   pidx    = (const int*)  d_in[0];
    const float* pos     = (const float*)d_in[1];
    const float* xs      = (const float*)d_in[2];
    const float* kernels = (const float*)d_in[3];
    const float* biases  = (const float*)d_in[4];
    float*       out     = (float*)d_out;
    int n = in_sizes[0];   // 32768

    // ws layout: cnt[NCELLS] ints | ent[NCELLS*CAP] int2
    int*  cnt = (int*)d_ws;
    int2* ent = (int2*)((char*)d_ws + (size_t)NCELLS * sizeof(int));

    int cap = CAP;
    size_t avail = (ws_size > (size_t)NCELLS * sizeof(int))
                 ? (ws_size - (size_t)NCELLS * sizeof(int)) / (sizeof(int2) * NCELLS)
                 : 0;
    if ((size_t)cap > avail) cap = (int)avail;

    hipMemsetAsync(cnt, 0, NCELLS * sizeof(int), stream);

    int eblocks = (n * 8 + 255) / 256;
    k_scatter<<<eblocks, 256, 0, stream>>>(pidx, pos, cnt, ent, out, out_size, n, cap);
    k_main  <<<NCELLS, 256, 0, stream>>>(xs, kernels, biases, cnt, ent, out, cap);
}